// Round 1
// baseline (351.756 us; speedup 1.0000x reference)
//
#include <hip/hip_runtime.h>

#define DEVINL __device__ __forceinline__

DEVINL float fexp2(float x){ return __builtin_amdgcn_exp2f(x); }
DEVINL float frcp (float x){ return __builtin_amdgcn_rcpf(x); }
// sigmoid(v) = 1/(1+exp(-v)) = 1/(1+2^(-v*log2e))
DEVINL float fsigmoid(float v){ return frcp(1.f + fexp2(-1.4426950408889634f * v)); }
// tanh(v) = 1 - 2/(1+exp(2v)); exp overflow -> inf -> 1, underflow -> 0 -> -1 (correct limits)
DEVINL float ftanh_(float v){ return 1.f - 2.f * frcp(1.f + fexp2(2.885390081777927f * v)); }

template<int E>
DEVINL void load_emb(const float* __restrict__ emb, int idx, float* Ed){
  if constexpr (E == 8){
    const float4* p = reinterpret_cast<const float4*>(emb + (size_t)idx * 8); // rows 32B-aligned
    float4 a = p[0], b = p[1];
    Ed[0]=a.x; Ed[1]=a.y; Ed[2]=a.z; Ed[3]=a.w;
    Ed[4]=b.x; Ed[5]=b.y; Ed[6]=b.z; Ed[7]=b.w;
  } else { // E == 10, rows 40B-aligned -> use float2 (8B alignment guaranteed)
    const float2* p = reinterpret_cast<const float2*>(emb + (size_t)idx * 10);
#pragma unroll
    for (int j=0;j<5;j++){ float2 v = p[j]; Ed[2*j]=v.x; Ed[2*j+1]=v.y; }
  }
}

// One group of H lanes handles one (batch, direction) sequence.
// Lane i owns gate rows {i, H+i, 2H+i} of Wih/Whh (register-resident).
// h broadcast each step via per-group LDS slot (within-wave only: no barriers).
template<int H, int GPW>
__global__ __launch_bounds__(256) void gru_kernel(
    const int*   __restrict__ seq,   const float* __restrict__ tim,
    const float* __restrict__ emb,
    const float* __restrict__ Wih_f, const float* __restrict__ Whh_f,
    const float* __restrict__ bih_f, const float* __restrict__ bhh_f,
    const float* __restrict__ Wih_b, const float* __restrict__ Whh_b,
    const float* __restrict__ bih_b, const float* __restrict__ bhh_b,
    const float* __restrict__ fc_w,      // (2H) score weights
    const float* __restrict__ fc_all_w,  // tail weight at [tail_idx]
    int tail_idx,
    float* __restrict__ out)
{
  constexpr int E   = H - 1;
  constexpr int S   = 512;
  constexpr int GPB = 4 * GPW;           // 4 waves / block
  __shared__ float hbuf[GPB * 20];       // stride 20 floats: b128 reads bank-disjoint

  const int tid  = threadIdx.x;
  const int wave = tid >> 6, lane = tid & 63;
  const int g_in_wave = lane / H;
  const int li = lane - g_in_wave * H;   // hidden element owned by this lane
  if (g_in_wave >= GPW) return;
  const int gid = blockIdx.x * GPB + wave * GPW + g_in_wave;
  if (gid >= 8192) return;
  const int b   = gid & 4095;
  const int dir = gid >> 12;             // 0 = fwd, 1 = bwd

  const float* Wih = dir ? Wih_b : Wih_f;
  const float* Whh = dir ? Whh_b : Whh_f;
  const float* bih = dir ? bih_b : bih_f;
  const float* bhh = dir ? bhh_b : bhh_f;

  float Wr[H], Wz[H], Wn[H], Ur[H], Uz[H], Un[H];
#pragma unroll
  for (int k=0;k<H;k++){
    Wr[k] = Wih[(size_t)( li      )*H + k];
    Wz[k] = Wih[(size_t)( H  + li )*H + k];
    Wn[k] = Wih[(size_t)(2*H + li )*H + k];
    Ur[k] = Whh[(size_t)( li      )*H + k];
    Uz[k] = Whh[(size_t)( H  + li )*H + k];
    Un[k] = Whh[(size_t)(2*H + li )*H + k];
  }
  const float br  = bih[li]     + bhh[li];
  const float bz  = bih[H+li]   + bhh[H+li];
  const float bxn = bih[2*H+li];
  const float bhn = bhh[2*H+li];

  const int*   sp = seq + (size_t)b * S;
  const float* tp = tim + (size_t)b * S;

  float h[H];
#pragma unroll
  for (int k=0;k<H;k++) h[k] = 0.f;
  float hmine = 0.f, prev = 0.f;

  const int gb = (wave * GPW + g_in_wave) * 20;  // float offset of this group's LDS slot

  // ---- chunk 0 (4 steps of idx/time), reversed in-register for bwd ----
  int ic[4]  = {0,0,0,0};  float tc[4]  = {0,0,0,0};
  int icn[4] = {0,0,0,0};  float tcn[4] = {0,0,0,0};
  {
    const int p0 = dir ? 508 : 0;
    int4   iv = *reinterpret_cast<const int4*  >(sp + p0);
    float4 tv = *reinterpret_cast<const float4*>(tp + p0);
    if (dir){ ic[0]=iv.w; ic[1]=iv.z; ic[2]=iv.y; ic[3]=iv.x;
              tc[0]=tv.w; tc[1]=tv.z; tc[2]=tv.y; tc[3]=tv.x; }
    else    { ic[0]=iv.x; ic[1]=iv.y; ic[2]=iv.z; ic[3]=iv.w;
              tc[0]=tv.x; tc[1]=tv.y; tc[2]=tv.z; tc[3]=tv.w; }
  }
  float Ec[E], En[E];
  load_emb<E>(emb, ic[0], Ec);

#pragma unroll 1
  for (int c = 0; c < S/4; c++){
    if (c < S/4 - 1){
      const int p0 = dir ? (508 - 4*(c+1)) : (4*(c+1));
      int4   iv = *reinterpret_cast<const int4*  >(sp + p0);
      float4 tv = *reinterpret_cast<const float4*>(tp + p0);
      if (dir){ icn[0]=iv.w; icn[1]=iv.z; icn[2]=iv.y; icn[3]=iv.x;
                tcn[0]=tv.w; tcn[1]=tv.z; tcn[2]=tv.y; tcn[3]=tv.x; }
      else    { icn[0]=iv.x; icn[1]=iv.y; icn[2]=iv.z; icn[3]=iv.w;
                tcn[0]=tv.x; tcn[1]=tv.y; tcn[2]=tv.z; tcn[3]=tv.w; }
    }
#pragma unroll
    for (int k=0;k<4;k++){
      // prefetch next step's embedding row (hides L2 gather latency under compute)
      const int nidx = (k < 3) ? ic[k+1] : icn[0];
      if ((k < 3) || (c < S/4 - 1)) load_emb<E>(emb, nidx, En);

      const float tcur = tc[k];
      const float dt = fmaxf(tcur - prev, 0.f); prev = tcur;

      float ar = br, az = bz, an = bxn, hn = bhn;
#pragma unroll
      for (int q=0;q<E;q++){
        ar = fmaf(Wr[q], Ec[q], ar);
        az = fmaf(Wz[q], Ec[q], az);
        an = fmaf(Wn[q], Ec[q], an);
      }
      ar = fmaf(Wr[E], dt, ar);
      az = fmaf(Wz[E], dt, az);
      an = fmaf(Wn[E], dt, an);
#pragma unroll
      for (int q=0;q<H;q++){
        ar = fmaf(Ur[q], h[q], ar);
        az = fmaf(Uz[q], h[q], az);
        hn = fmaf(Un[q], h[q], hn);
      }
      const float r = fsigmoid(ar);
      const float z = fsigmoid(az);
      const float n = ftanh_(fmaf(r, hn, an));
      hmine = fmaf(z, hmine - n, n);          // (1-z)*n + z*h

      hbuf[gb + li] = hmine;                  // publish my element
      __builtin_amdgcn_wave_barrier();
      asm volatile("" ::: "memory");          // keep write before reads (in-order DS pipe does the rest)

      float4 h03 = *reinterpret_cast<const float4*>(&hbuf[gb]);
      float4 h47 = *reinterpret_cast<const float4*>(&hbuf[gb+4]);
      h[0]=h03.x; h[1]=h03.y; h[2]=h03.z; h[3]=h03.w;
      h[4]=h47.x; h[5]=h47.y; h[6]=h47.z; h[7]=h47.w;
      if constexpr (H == 9){
        h[8] = hbuf[gb+8];
      } else {
        float4 h8b = *reinterpret_cast<const float4*>(&hbuf[gb+8]);
        h[8]=h8b.x; h[9]=h8b.y; h[10]=h8b.z;
      }
#pragma unroll
      for (int q=0;q<E;q++) Ec[q] = En[q];
    }
#pragma unroll
    for (int k=0;k<4;k++){ ic[k]=icn[k]; tc[k]=tcn[k]; }
  }

  // final: score contribution, one atomic per group
  if (li == 0){
    float dot = 0.f;
#pragma unroll
    for (int q=0;q<H;q++) dot = fmaf(fc_w[dir*H + q], h[q], dot);
    atomicAdd(out + b, fc_all_w[tail_idx] * dot);
  }
}

__global__ __launch_bounds__(256) void base_kernel(
    const float* __restrict__ stat,
    const float* __restrict__ fc_all_w, const float* __restrict__ fc_all_b,
    const float* __restrict__ fc_dp_b,  const float* __restrict__ fc_cp_b,
    float* __restrict__ out)
{
  const int b = blockIdx.x * 256 + threadIdx.x;
  if (b >= 4096) return;
  float s = fc_all_b[0] + fc_all_w[20]*fc_dp_b[0] + fc_all_w[21]*fc_cp_b[0];
  const float* st = stat + (size_t)b * 20;
#pragma unroll
  for (int k=0;k<20;k++) s = fmaf(fc_all_w[k], st[k], s);
  out[b] = s;
}

extern "C" void kernel_launch(void* const* d_in, const int* in_sizes, int n_in,
                              void* d_out, int out_size, void* d_ws, size_t ws_size,
                              hipStream_t stream)
{
  const float* stat   = (const float*)d_in[0];
  const int*   dp     = (const int*)  d_in[1];
  const int*   cp     = (const int*)  d_in[2];
  const float* dp_t   = (const float*)d_in[3];
  const float* cp_t   = (const float*)d_in[4];
  const float* emb_dp = (const float*)d_in[5];
  const float* emb_cp = (const float*)d_in[6];

  const float* Wih_dpf = (const float*)d_in[7];
  const float* Whh_dpf = (const float*)d_in[8];
  const float* bih_dpf = (const float*)d_in[9];
  const float* bhh_dpf = (const float*)d_in[10];
  const float* Wih_dpb = (const float*)d_in[11];
  const float* Whh_dpb = (const float*)d_in[12];
  const float* bih_dpb = (const float*)d_in[13];
  const float* bhh_dpb = (const float*)d_in[14];
  const float* Wih_cpf = (const float*)d_in[15];
  const float* Whh_cpf = (const float*)d_in[16];
  const float* bih_cpf = (const float*)d_in[17];
  const float* bhh_cpf = (const float*)d_in[18];
  const float* Wih_cpb = (const float*)d_in[19];
  const float* Whh_cpb = (const float*)d_in[20];
  const float* bih_cpb = (const float*)d_in[21];
  const float* bhh_cpb = (const float*)d_in[22];

  const float* fc_dp_w  = (const float*)d_in[23];
  const float* fc_dp_b  = (const float*)d_in[24];
  const float* fc_cp_w  = (const float*)d_in[25];
  const float* fc_cp_b  = (const float*)d_in[26];
  const float* fc_all_w = (const float*)d_in[27];
  const float* fc_all_b = (const float*)d_in[28];

  float* out = (float*)d_out;

  // static part of out[b] (idempotent full overwrite), then GRU atomics accumulate
  base_kernel<<<16, 256, 0, stream>>>(stat, fc_all_w, fc_all_b, fc_dp_b, fc_cp_b, out);

  // dp GRUs: H=9, 7 groups/wave, 28 groups/block; 8192 groups (fwd+bwd)
  {
    constexpr int GPB = 4 * 7;
    const int blocks = (8192 + GPB - 1) / GPB;
    gru_kernel<9,7><<<blocks, 256, 0, stream>>>(
        dp, dp_t, emb_dp,
        Wih_dpf, Whh_dpf, bih_dpf, bhh_dpf,
        Wih_dpb, Whh_dpb, bih_dpb, bhh_dpb,
        fc_dp_w, fc_all_w, 20, out);
  }
  // cp GRUs: H=11, 5 groups/wave, 20 groups/block
  {
    constexpr int GPB = 4 * 5;
    const int blocks = (8192 + GPB - 1) / GPB;
    gru_kernel<11,5><<<blocks, 256, 0, stream>>>(
        cp, cp_t, emb_cp,
        Wih_cpf, Whh_cpf, bih_cpf, bhh_cpf,
        Wih_cpb, Whh_cpb, bih_cpb, bhh_cpb,
        fc_cp_w, fc_all_w, 21, out);
  }
}

// Round 2
// 201.475 us; speedup vs baseline: 1.7459x; 1.7459x over previous
//
#include <hip/hip_runtime.h>

#define DEVINL __device__ __forceinline__

DEVINL float fexp2(float x){ return __builtin_amdgcn_exp2f(x); }
DEVINL float frcp (float x){ return __builtin_amdgcn_rcpf(x); }
// sigmoid(v) = 1/(1+2^(-v*log2e))
DEVINL float fsigmoid(float v){ return frcp(1.f + fexp2(-1.4426950408889634f * v)); }
// tanh(v) = 1 - 2/(1+2^(2v*log2e)); saturates correctly at +-inf
DEVINL float ftanh_(float v){ return 1.f - 2.f * frcp(1.f + fexp2(2.885390081777927f * v)); }

// ---------------------------------------------------------------------------
// Kernel 1: precompute per-(dir, idx, lane) input-gate table
//   G = { Wr_emb·e + bih_r + bhh_r,  Wz_emb·e + bih_z + bhh_z,  Wn_emb·e + bih_n, 0 }
// plus the static part of out[b].
// ---------------------------------------------------------------------------
template<int H, int NE>
DEVINL void pre_entry(int t, const float* __restrict__ emb,
                      const float* __restrict__ Wih_f, const float* __restrict__ bih_f, const float* __restrict__ bhh_f,
                      const float* __restrict__ Wih_b, const float* __restrict__ bih_b, const float* __restrict__ bhh_b,
                      float4* __restrict__ G, int N)
{
  constexpr int E = H - 1;
  const int dir = t / (N * H);
  const int r   = t - dir * (N * H);
  const int idx = r / H;
  const int li  = r - idx * H;
  const float* Wih = dir ? Wih_b : Wih_f;
  const float* bih = dir ? bih_b : bih_f;
  const float* bhh = dir ? bhh_b : bhh_f;
  const float* e = emb + (size_t)idx * E;
  float gr = bih[li]       + bhh[li];
  float gz = bih[H + li]   + bhh[H + li];
  float gn = bih[2*H + li];
#pragma unroll
  for (int q = 0; q < E; q++){
    const float ev = e[q];
    gr = fmaf(Wih[(size_t)( li     )*H + q], ev, gr);
    gz = fmaf(Wih[(size_t)( H + li )*H + q], ev, gz);
    gn = fmaf(Wih[(size_t)(2*H + li)*H + q], ev, gn);
  }
  G[(size_t)(dir * N + idx) * H + li] = make_float4(gr, gz, gn, 0.f);
}

__global__ __launch_bounds__(256) void pre_kernel(
    const float* __restrict__ emb_dp, const float* __restrict__ emb_cp,
    const float* __restrict__ Wih_dpf, const float* __restrict__ bih_dpf, const float* __restrict__ bhh_dpf,
    const float* __restrict__ Wih_dpb, const float* __restrict__ bih_dpb, const float* __restrict__ bhh_dpb,
    const float* __restrict__ Wih_cpf, const float* __restrict__ bih_cpf, const float* __restrict__ bhh_cpf,
    const float* __restrict__ Wih_cpb, const float* __restrict__ bih_cpb, const float* __restrict__ bhh_cpb,
    const float* __restrict__ stat, const float* __restrict__ fc_all_w, const float* __restrict__ fc_all_b,
    const float* __restrict__ fc_dp_b, const float* __restrict__ fc_cp_b,
    float4* __restrict__ Gdp, float4* __restrict__ Gcp, float* __restrict__ out)
{
  constexpr int NDP_E = 2 * 4096 * 9;    // 73728
  constexpr int NCP_E = 2 * 10000 * 11;  // 220000
  const int t = blockIdx.x * 256 + threadIdx.x;
  if (t < NDP_E){
    pre_entry<9, 8>(t, emb_dp, Wih_dpf, bih_dpf, bhh_dpf, Wih_dpb, bih_dpb, bhh_dpb, Gdp, 4096);
  } else if (t < NDP_E + NCP_E){
    pre_entry<11, 10>(t - NDP_E, emb_cp, Wih_cpf, bih_cpf, bhh_cpf, Wih_cpb, bih_cpb, bhh_cpb, Gcp, 10000);
  } else if (t < NDP_E + NCP_E + 4096){
    const int b = t - (NDP_E + NCP_E);
    float s = fc_all_b[0] + fc_all_w[20]*fc_dp_b[0] + fc_all_w[21]*fc_cp_b[0];
    const float* st = stat + (size_t)b * 20;
#pragma unroll
    for (int k = 0; k < 20; k++) s = fmaf(fc_all_w[k], st[k], s);
    out[b] = s;
  }
}

// ---------------------------------------------------------------------------
// Kernel 2: fused GRU. One group of H lanes per (batch, direction) sequence.
// Per-step input gates come from the precomputed table (one float4 gather).
// h broadcast via per-group LDS slot, within-wave only (no barriers).
// ---------------------------------------------------------------------------
template<int H, int GPW, int N>
DEVINL void gru_body(int blk,
    const int*   __restrict__ seq,  const float* __restrict__ tim,
    const float4* __restrict__ Gtab,
    const float* __restrict__ Wih_f, const float* __restrict__ Whh_f, const float* __restrict__ bhh_f,
    const float* __restrict__ Wih_b, const float* __restrict__ Whh_b, const float* __restrict__ bhh_b,
    const float* __restrict__ fc_w, const float* __restrict__ fc_all_w, int tail_idx,
    float* __restrict__ out, float* hbuf)
{
  constexpr int S   = 512;
  constexpr int GPB = 4 * GPW;

  const int tid  = threadIdx.x;
  const int wave = tid >> 6, lane = tid & 63;
  const int g_in_wave = lane / H;
  const int li = lane - g_in_wave * H;
  if (g_in_wave >= GPW) return;
  const int gid = blk * GPB + wave * GPW + g_in_wave;
  if (gid >= 8192) return;
  const int b   = gid & 4095;
  const int dir = gid >> 12;

  const float* Wih = dir ? Wih_b : Wih_f;
  const float* Whh = dir ? Whh_b : Whh_f;

  // dt-column weights + recurrent rows, register-resident
  const float Wrd = Wih[(size_t)( li     )*H + (H-1)];
  const float Wzd = Wih[(size_t)( H + li )*H + (H-1)];
  const float Wnd = Wih[(size_t)(2*H + li)*H + (H-1)];
  float Ur[H], Uz[H], Un[H];
#pragma unroll
  for (int k = 0; k < H; k++){
    Ur[k] = Whh[(size_t)( li     )*H + k];
    Uz[k] = Whh[(size_t)( H + li )*H + k];
    Un[k] = Whh[(size_t)(2*H + li)*H + k];
  }
  const float bhn = (dir ? bhh_b : bhh_f)[2*H + li];

  const int*    sp = seq + (size_t)b * S;
  const float*  tp = tim + (size_t)b * S;
  const float4* pG = Gtab + (size_t)(dir * N) * H + li;   // + idx*H per step

  float h[H];
#pragma unroll
  for (int k = 0; k < H; k++) h[k] = 0.f;
  float hmine = 0.f, prev = 0.f;

  const int gb = (wave * GPW + g_in_wave) * 20;

  // chunk 0 indices/times (reversed in-register for bwd)
  int ic[4]  = {0,0,0,0};  float tc[4]  = {0,0,0,0};
  int icn[4] = {0,0,0,0};  float tcn[4] = {0,0,0,0};
  {
    const int p0 = dir ? 508 : 0;
    int4   iv = *reinterpret_cast<const int4*  >(sp + p0);
    float4 tv = *reinterpret_cast<const float4*>(tp + p0);
    if (dir){ ic[0]=iv.w; ic[1]=iv.z; ic[2]=iv.y; ic[3]=iv.x;
              tc[0]=tv.w; tc[1]=tv.z; tc[2]=tv.y; tc[3]=tv.x; }
    else    { ic[0]=iv.x; ic[1]=iv.y; ic[2]=iv.z; ic[3]=iv.w;
              tc[0]=tv.x; tc[1]=tv.y; tc[2]=tv.z; tc[3]=tv.w; }
  }

  // ring-4 table prefetch, 2 steps deep (all indices compile-time after unroll)
  float4 Gb[4];
  Gb[0] = pG[(size_t)ic[0] * H];
  Gb[1] = pG[(size_t)ic[1] * H];

#pragma unroll 1
  for (int c = 0; c < S/4; c++){
    if (c < S/4 - 1){
      const int p0 = dir ? (508 - 4*(c+1)) : (4*(c+1));
      int4   iv = *reinterpret_cast<const int4*  >(sp + p0);
      float4 tv = *reinterpret_cast<const float4*>(tp + p0);
      if (dir){ icn[0]=iv.w; icn[1]=iv.z; icn[2]=iv.y; icn[3]=iv.x;
                tcn[0]=tv.w; tcn[1]=tv.z; tcn[2]=tv.y; tcn[3]=tv.x; }
      else    { icn[0]=iv.x; icn[1]=iv.y; icn[2]=iv.z; icn[3]=iv.w;
                tcn[0]=tv.x; tcn[1]=tv.y; tcn[2]=tv.z; tcn[3]=tv.w; }
    }
#pragma unroll
    for (int k = 0; k < 4; k++){
      const float4 g4 = Gb[k];
      // prefetch step (c*4 + k + 2); on the last chunk icn aliases valid in-range
      // indices from the previous chunk, so the speculative load is always safe.
      {
        const int pidx = (k==0) ? ic[2] : (k==1) ? ic[3] : (k==2) ? icn[0] : icn[1];
        Gb[(k+2)&3] = pG[(size_t)pidx * H];
      }

      const float tcur = tc[k];
      const float dt = fmaxf(tcur - prev, 0.f); prev = tcur;

      float ar0 = fmaf(Wrd, dt, g4.x), ar1 = 0.f;
      float az0 = fmaf(Wzd, dt, g4.y), az1 = 0.f;
      float an  = fmaf(Wnd, dt, g4.z);
      float hn0 = bhn, hn1 = 0.f;
#pragma unroll
      for (int q = 0; q < H; q += 2){
        ar0 = fmaf(Ur[q], h[q], ar0);
        az0 = fmaf(Uz[q], h[q], az0);
        hn0 = fmaf(Un[q], h[q], hn0);
      }
#pragma unroll
      for (int q = 1; q < H; q += 2){
        ar1 = fmaf(Ur[q], h[q], ar1);
        az1 = fmaf(Uz[q], h[q], az1);
        hn1 = fmaf(Un[q], h[q], hn1);
      }
      const float r = fsigmoid(ar0 + ar1);
      const float z = fsigmoid(az0 + az1);
      const float n = ftanh_(fmaf(r, hn0 + hn1, an));
      hmine = fmaf(z, hmine - n, n);     // (1-z)*n + z*h

      hbuf[gb + li] = hmine;
      __builtin_amdgcn_wave_barrier();
      asm volatile("" ::: "memory");     // in-order DS pipe: write lands before reads

      float4 h03 = *reinterpret_cast<const float4*>(&hbuf[gb]);
      float4 h47 = *reinterpret_cast<const float4*>(&hbuf[gb+4]);
      h[0]=h03.x; h[1]=h03.y; h[2]=h03.z; h[3]=h03.w;
      h[4]=h47.x; h[5]=h47.y; h[6]=h47.z; h[7]=h47.w;
      if constexpr (H == 9){
        h[8] = hbuf[gb+8];
      } else {
        float4 h8b = *reinterpret_cast<const float4*>(&hbuf[gb+8]);
        h[8]=h8b.x; h[9]=h8b.y; h[10]=h8b.z;
      }
    }
#pragma unroll
    for (int k = 0; k < 4; k++){ ic[k]=icn[k]; tc[k]=tcn[k]; }
  }

  if (li == 0){
    float dot = 0.f;
#pragma unroll
    for (int q = 0; q < H; q++) dot = fmaf(fc_w[dir*H + q], h[q], dot);
    atomicAdd(out + b, fc_all_w[tail_idx] * dot);
  }
}

__global__ __launch_bounds__(256) void gru_fused(
    const int* __restrict__ dp,  const float* __restrict__ dp_t,
    const int* __restrict__ cp,  const float* __restrict__ cp_t,
    const float4* __restrict__ Gdp, const float4* __restrict__ Gcp,
    const float* __restrict__ Wih_dpf, const float* __restrict__ Whh_dpf, const float* __restrict__ bhh_dpf,
    const float* __restrict__ Wih_dpb, const float* __restrict__ Whh_dpb, const float* __restrict__ bhh_dpb,
    const float* __restrict__ Wih_cpf, const float* __restrict__ Whh_cpf, const float* __restrict__ bhh_cpf,
    const float* __restrict__ Wih_cpb, const float* __restrict__ Whh_cpb, const float* __restrict__ bhh_cpb,
    const float* __restrict__ fc_dp_w, const float* __restrict__ fc_cp_w, const float* __restrict__ fc_all_w,
    float* __restrict__ out, int DP_BLOCKS)
{
  __shared__ float hbuf[28 * 20];
  if ((int)blockIdx.x < DP_BLOCKS){
    gru_body<9, 7, 4096>(blockIdx.x, dp, dp_t, Gdp,
        Wih_dpf, Whh_dpf, bhh_dpf, Wih_dpb, Whh_dpb, bhh_dpb,
        fc_dp_w, fc_all_w, 20, out, hbuf);
  } else {
    gru_body<11, 5, 10000>(blockIdx.x - DP_BLOCKS, cp, cp_t, Gcp,
        Wih_cpf, Whh_cpf, bhh_cpf, Wih_cpb, Whh_cpb, bhh_cpb,
        fc_cp_w, fc_all_w, 21, out, hbuf);
  }
}

extern "C" void kernel_launch(void* const* d_in, const int* in_sizes, int n_in,
                              void* d_out, int out_size, void* d_ws, size_t ws_size,
                              hipStream_t stream)
{
  const float* stat   = (const float*)d_in[0];
  const int*   dp     = (const int*)  d_in[1];
  const int*   cp     = (const int*)  d_in[2];
  const float* dp_t   = (const float*)d_in[3];
  const float* cp_t   = (const float*)d_in[4];
  const float* emb_dp = (const float*)d_in[5];
  const float* emb_cp = (const float*)d_in[6];

  const float* Wih_dpf = (const float*)d_in[7];
  const float* Whh_dpf = (const float*)d_in[8];
  const float* bih_dpf = (const float*)d_in[9];
  const float* bhh_dpf = (const float*)d_in[10];
  const float* Wih_dpb = (const float*)d_in[11];
  const float* Whh_dpb = (const float*)d_in[12];
  const float* bih_dpb = (const float*)d_in[13];
  const float* bhh_dpb = (const float*)d_in[14];
  const float* Wih_cpf = (const float*)d_in[15];
  const float* Whh_cpf = (const float*)d_in[16];
  const float* bih_cpf = (const float*)d_in[17];
  const float* bhh_cpf = (const float*)d_in[18];
  const float* Wih_cpb = (const float*)d_in[19];
  const float* Whh_cpb = (const float*)d_in[20];
  const float* bih_cpb = (const float*)d_in[21];
  const float* bhh_cpb = (const float*)d_in[22];

  const float* fc_dp_w  = (const float*)d_in[23];
  const float* fc_dp_b  = (const float*)d_in[24];
  const float* fc_cp_w  = (const float*)d_in[25];
  const float* fc_cp_b  = (const float*)d_in[26];
  const float* fc_all_w = (const float*)d_in[27];
  const float* fc_all_b = (const float*)d_in[28];

  float* out = (float*)d_out;

  // workspace layout: dp table (2*4096*9 float4 = 1.18 MB), cp table (2*10000*11 float4 = 3.52 MB)
  float4* Gdp = (float4*)d_ws;
  float4* Gcp = (float4*)((char*)d_ws + (size_t)(2*4096*9) * sizeof(float4));

  // kernel 1: tables + static part of out
  {
    const int total = 2*4096*9 + 2*10000*11 + 4096;
    const int blocks = (total + 255) / 256;
    pre_kernel<<<blocks, 256, 0, stream>>>(
        emb_dp, emb_cp,
        Wih_dpf, bih_dpf, bhh_dpf, Wih_dpb, bih_dpb, bhh_dpb,
        Wih_cpf, bih_cpf, bhh_cpf, Wih_cpb, bih_cpb, bhh_cpb,
        stat, fc_all_w, fc_all_b, fc_dp_b, fc_cp_b,
        Gdp, Gcp, out);
  }

  // kernel 2: fused GRUs (dp blocks first, then cp blocks)
  {
    const int DP_BLOCKS = (8192 + 27) / 28;   // H=9, 7 groups/wave
    const int CP_BLOCKS = (8192 + 19) / 20;   // H=11, 5 groups/wave
    gru_fused<<<DP_BLOCKS + CP_BLOCKS, 256, 0, stream>>>(
        dp, dp_t, cp, cp_t, Gdp, Gcp,
        Wih_dpf, Whh_dpf, bhh_dpf, Wih_dpb, Whh_dpb, bhh_dpb,
        Wih_cpf, Whh_cpf, bhh_cpf, Wih_cpb, Whh_cpb, bhh_cpb,
        fc_dp_w, fc_cp_w, fc_all_w, out, DP_BLOCKS);
  }
}